// Round 4
// baseline (237.475 us; speedup 1.0000x reference)
//
#include <hip/hip_runtime.h>

// Row-decomposed forward-kinematics chain.
// Each output frame F is affine with constant bottom row (0,0,0,1), and every
// joint update is columnwise: f0' = a*f0 + b*f2 etc. Therefore row r of F
// evolves independently: state (f0r,f1r,f2r,f3r) -> exactly one output float4.
// 4 lanes per element (lane sub = row). Stores: lane writes float4 at
// i*32 + frame*4 + sub -> each aligned 4-lane group emits one full 64B line.

__global__ __launch_bounds__(256) void fk_chain_kernel(const float* __restrict__ q,
                                                       float4* __restrict__ out,
                                                       int n)
{
    const long long g = (long long)blockIdx.x * blockDim.x + threadIdx.x;
    const long long i = g >> 2;          // element index
    const int sub = (int)(g & 3);        // row index 0..3
    if (i >= n) return;

    const float* qi = q + i * 7;
    const float HPI = 1.57079632679489662f;

    float qv[7];
    #pragma unroll
    for (int k = 0; k < 7; ++k) qv[k] = qi[k];

    float c[7], s[7];
    __sincosf(qv[0], &s[0], &c[0]);
    __sincosf(qv[1], &s[1], &c[1]);
    __sincosf(qv[2] - HPI, &s[2], &c[2]);
    __sincosf(qv[3], &s[3], &c[3]);
    __sincosf(qv[4], &s[4], &c[4]);
    __sincosf(qv[5] + HPI, &s[5], &c[5]);
    __sincosf(qv[6] - HPI, &s[6], &c[6]);

    // Per-row scalar chain state: row sub of columns (f0, f1, f2, f3).
    // Frame 0 = m0: f0=(c0,s0,0), f1=(-s0,c0,0), f2=(0,0,1), f3=(0,0,0);
    // bottom row handled by the same formulas via (0,0,0,1) init.
    float f0r = (sub == 0) ? c[0] : ((sub == 1) ? s[0] : 0.f);
    float f1r = (sub == 0) ? -s[0] : ((sub == 1) ? c[0] : 0.f);
    float f2r = (sub == 2) ? 1.f : 0.f;
    float f3r = (sub == 3) ? 1.f : 0.f;

    float4* ob = out + i * 32 + sub;     // row `sub` of frame j lives at +j*4

    // frame 0
    ob[0] = make_float4(f0r, f1r, f2r, f3r);

    // "type A" joint (m1, m3, m5, m6): f0'=c*f0+s*f2; f1'=c*f2-s*f0; f2'=-f1
    #define TYPE_A(cc, ss)                          \
        {                                           \
            float t0 = (cc) * f0r + (ss) * f2r;     \
            float t1 = (cc) * f2r - (ss) * f0r;     \
            float t2 = -f1r;                        \
            f0r = t0; f1r = t1; f2r = t2;           \
        }

    // m1 -> frame 1
    TYPE_A(c[1], s[1]);
    ob[4] = make_float4(f0r, f1r, f2r, f3r);

    // m2 -> frame 2: f0'=c*f0-s*f2; f1'=-(s*f0+c*f2); f2'=f1; f3+=0.4*f1
    {
        float t0 = c[2] * f0r - s[2] * f2r;
        float t1 = -(s[2] * f0r + c[2] * f2r);
        float t2 = f1r;
        f3r = 0.4f * f1r + f3r;
        f0r = t0; f1r = t1; f2r = t2;
    }
    ob[8] = make_float4(f0r, f1r, f2r, f3r);

    // m3 -> frame 3
    TYPE_A(c[3], s[3]);
    ob[12] = make_float4(f0r, f1r, f2r, f3r);

    // m4 -> frame 4: f0'=s*f2-c*f0; f1'=s*f0+c*f2; f2'=f1; f3+=0.39*f1
    {
        float t0 = s[4] * f2r - c[4] * f0r;
        float t1 = s[4] * f0r + c[4] * f2r;
        float t2 = f1r;
        f3r = 0.39f * f1r + f3r;
        f0r = t0; f1r = t1; f2r = t2;
    }
    ob[16] = make_float4(f0r, f1r, f2r, f3r);

    // m5 -> frame 5
    TYPE_A(c[5], s[5]);
    ob[20] = make_float4(f0r, f1r, f2r, f3r);

    // m6 -> frame 6
    TYPE_A(c[6], s[6]);
    ob[24] = make_float4(f0r, f1r, f2r, f3r);

    // m7 -> frame 7: f0'=-f0; f1'=f2; f2'=f1; f3+=0.118*f1
    {
        float t0 = -f0r;
        float t1 = f2r;
        float t2 = f1r;
        f3r = 0.118f * f1r + f3r;
        f0r = t0; f1r = t1; f2r = t2;
    }
    ob[28] = make_float4(f0r, f1r, f2r, f3r);

    #undef TYPE_A
}

extern "C" void kernel_launch(void* const* d_in, const int* in_sizes, int n_in,
                              void* d_out, int out_size, void* d_ws, size_t ws_size,
                              hipStream_t stream) {
    const float* x = (const float*)d_in[0];
    float* out = (float*)d_out;
    int n = in_sizes[0] / 7;                       // 2,000,000 elements
    long long threads = (long long)n * 4;          // 4 lanes per element
    int block = 256;
    long long grid = (threads + block - 1) / block;
    fk_chain_kernel<<<(int)grid, block, 0, stream>>>(x, (float4*)out, n);
}

// Round 5
// 214.631 us; speedup vs baseline: 1.1064x; 1.1064x over previous
//
#include <hip/hip_runtime.h>

// Forward-kinematics chain, pipelined LDS-transpose writer.
// - Row 3 of every output frame is (0,0,0,1): synthesized at flush, not staged.
// - Per 64-elem group: stage 8 frames x 3 rows per lane (24 float4, stride 25),
//   then flush as 32 fully-contiguous 1KB wave stores (dense 32KB span).
// - Double-buffered: while flushing group g, compute+stage group g+1 in the
//   same wave -> store issue overlaps compute (fill-kernel-like duty cycle).

#define GROUPS_PER_BLOCK 8
#define LSTRIDE 25  // 24 payload float4 + 1 pad (100 dwords = 4 mod 32: conflict-free residue)

namespace {

struct V3 { float x, y, z; };
__device__ __forceinline__ V3 v3(float x, float y, float z) { return {x, y, z}; }

// Stage rows 0..2 of a frame: p[r] = (c0[r], c1[r], c2[r], c3[r])
__device__ __forceinline__ void stage3(float4* p, V3 c0, V3 c1, V3 c2, V3 c3) {
    p[0] = make_float4(c0.x, c1.x, c2.x, c3.x);
    p[1] = make_float4(c0.y, c1.y, c2.y, c3.y);
    p[2] = make_float4(c0.z, c1.z, c2.z, c3.z);
}

__device__ __forceinline__ void compute_stage(const float* __restrict__ q,
                                              float4* __restrict__ buf,
                                              int lane, long long grp, long long n)
{
    long long i = grp * 64 + lane;
    if (i >= n) i = n - 1;  // clamp; flush guards the stores
    const float* qi = q + i * 7;
    const float HPI = 1.57079632679489662f;

    float qv[7];
    #pragma unroll
    for (int k = 0; k < 7; ++k) qv[k] = qi[k];

    float c[7], s[7];
    __sincosf(qv[0], &s[0], &c[0]);
    __sincosf(qv[1], &s[1], &c[1]);
    __sincosf(qv[2] - HPI, &s[2], &c[2]);
    __sincosf(qv[3], &s[3], &c[3]);
    __sincosf(qv[4], &s[4], &c[4]);
    __sincosf(qv[5] + HPI, &s[5], &c[5]);
    __sincosf(qv[6] - HPI, &s[6], &c[6]);

    float4* myS = buf + lane * LSTRIDE;

    // chain state: columns of current frame (bottom row implicit)
    V3 f0 = v3(c[0], s[0], 0.f);
    V3 f1 = v3(-s[0], c[0], 0.f);
    V3 f2 = v3(0.f, 0.f, 1.f);
    V3 f3 = v3(0.f, 0.f, 0.f);

    #define TYPE_A(cc, ss)                                              \
        {                                                               \
            V3 t0 = v3((cc)*f0.x + (ss)*f2.x, (cc)*f0.y + (ss)*f2.y, (cc)*f0.z + (ss)*f2.z); \
            V3 t1 = v3((cc)*f2.x - (ss)*f0.x, (cc)*f2.y - (ss)*f0.y, (cc)*f2.z - (ss)*f0.z); \
            V3 t2 = v3(-f1.x, -f1.y, -f1.z);                            \
            f0 = t0; f1 = t1; f2 = t2;                                  \
        }

    stage3(myS + 0, f0, f1, f2, f3);                     // frame 0 = m0

    TYPE_A(c[1], s[1]);                                  // m1
    stage3(myS + 3, f0, f1, f2, f3);

    // m2: f0' = c*f0 - s*f2; f1' = -(s*f0 + c*f2); f2' = f1; f3 += 0.4*f1
    {
        V3 t0 = v3(c[2]*f0.x - s[2]*f2.x, c[2]*f0.y - s[2]*f2.y, c[2]*f0.z - s[2]*f2.z);
        V3 t1 = v3(-(s[2]*f0.x + c[2]*f2.x), -(s[2]*f0.y + c[2]*f2.y), -(s[2]*f0.z + c[2]*f2.z));
        V3 t2 = f1;
        f3 = v3(0.4f*f1.x + f3.x, 0.4f*f1.y + f3.y, 0.4f*f1.z + f3.z);
        f0 = t0; f1 = t1; f2 = t2;
    }
    stage3(myS + 6, f0, f1, f2, f3);

    TYPE_A(c[3], s[3]);                                  // m3
    stage3(myS + 9, f0, f1, f2, f3);

    // m4: f0' = s*f2 - c*f0; f1' = s*f0 + c*f2; f2' = f1; f3 += 0.39*f1
    {
        V3 t0 = v3(s[4]*f2.x - c[4]*f0.x, s[4]*f2.y - c[4]*f0.y, s[4]*f2.z - c[4]*f0.z);
        V3 t1 = v3(s[4]*f0.x + c[4]*f2.x, s[4]*f0.y + c[4]*f2.y, s[4]*f0.z + c[4]*f2.z);
        V3 t2 = f1;
        f3 = v3(0.39f*f1.x + f3.x, 0.39f*f1.y + f3.y, 0.39f*f1.z + f3.z);
        f0 = t0; f1 = t1; f2 = t2;
    }
    stage3(myS + 12, f0, f1, f2, f3);

    TYPE_A(c[5], s[5]);                                  // m5
    stage3(myS + 15, f0, f1, f2, f3);

    TYPE_A(c[6], s[6]);                                  // m6
    stage3(myS + 18, f0, f1, f2, f3);

    // m7: f0' = -f0; f1' = f2; f2' = f1; f3 += 0.118*f1
    {
        V3 t0 = v3(-f0.x, -f0.y, -f0.z);
        V3 t1 = f2;
        V3 t2 = f1;
        f3 = v3(0.118f*f1.x + f3.x, 0.118f*f1.y + f3.y, 0.118f*f1.z + f3.z);
        f0 = t0; f1 = t1; f2 = t2;
    }
    stage3(myS + 21, f0, f1, f2, f3);

    #undef TYPE_A
}

__device__ __forceinline__ void flush_group(const float4* __restrict__ buf,
                                            float4* __restrict__ out,
                                            int lane, long long grp, long long n,
                                            bool full)
{
    const int p  = lane & 31;            // float4 index within element
    const int eh = lane >> 5;            // element half-select (0/1)
    const int f  = p >> 2;               // frame 0..7
    const int r  = p & 3;                // row 0..3
    const int rr = (r == 3) ? 2 : r;     // row 3 -> duplicate addr (broadcast), overridden
    const int base_off = eh * LSTRIDE + f * 3 + rr;
    const bool isr3 = (r == 3);
    float4* gb = out + grp * 2048;       // 64 elem * 32 float4

    if (full) {
        #pragma unroll
        for (int j = 0; j < 32; ++j) {
            float4 v = buf[j * (2 * LSTRIDE) + base_off];
            if (isr3) v = make_float4(0.f, 0.f, 0.f, 1.f);
            gb[j * 64 + lane] = v;
        }
    } else {
        #pragma unroll
        for (int j = 0; j < 32; ++j) {
            float4 v = buf[j * (2 * LSTRIDE) + base_off];
            if (isr3) v = make_float4(0.f, 0.f, 0.f, 1.f);
            long long e = (long long)((j * 64 + lane) >> 5);
            if (grp * 64 + e < n) gb[j * 64 + lane] = v;
        }
    }
}

} // namespace

__global__ __launch_bounds__(64) void fk_chain_kernel(const float* __restrict__ q,
                                                      float4* __restrict__ out,
                                                      int n, int ngroups)
{
    __shared__ float4 lds[2][64 * LSTRIDE];  // 2 x 25,600 B

    const int lane = threadIdx.x;            // block == 1 wave
    const long long g0 = (long long)blockIdx.x * GROUPS_PER_BLOCK;
    if (g0 >= ngroups) return;
    const int ng = (ngroups - g0 < GROUPS_PER_BLOCK) ? (int)(ngroups - g0)
                                                     : GROUPS_PER_BLOCK;

    compute_stage(q, lds[0], lane, g0, n);
    int cur = 0;
    for (int t = 1; t < ng; ++t) {
        __syncthreads();  // stage(t-1) writes + flush(t-2) reads complete
        compute_stage(q, lds[cur ^ 1], lane, g0 + t, n);      // overlaps with...
        bool full = ((g0 + t - 1) * 64 + 64 <= (long long)n);
        flush_group(lds[cur], out, lane, g0 + t - 1, n, full); // ...these stores
        cur ^= 1;
    }
    __syncthreads();
    bool full = ((g0 + ng - 1) * 64 + 64 <= (long long)n);
    flush_group(lds[cur], out, lane, g0 + ng - 1, n, full);
}

extern "C" void kernel_launch(void* const* d_in, const int* in_sizes, int n_in,
                              void* d_out, int out_size, void* d_ws, size_t ws_size,
                              hipStream_t stream) {
    const float* x = (const float*)d_in[0];
    float* out = (float*)d_out;
    int n = in_sizes[0] / 7;                     // 2,000,000 elements
    int ngroups = (n + 63) >> 6;                 // 31,250 groups of 64
    int grid = (ngroups + GROUPS_PER_BLOCK - 1) / GROUPS_PER_BLOCK;  // 3,907
    fk_chain_kernel<<<grid, 64, 0, stream>>>(x, (float4*)out, n, ngroups);
}

// Round 7
// 187.435 us; speedup vs baseline: 1.2670x; 1.1451x over previous
//
#include <hip/hip_runtime.h>

// FK chain, LDS-transpose writer (r3 structure, 3-row staging).
// - block = 1 wave (64 lanes) = 1 group of 64 elements. No cross-iteration
//   LDS reuse -> race-free by construction (r6's barrier-free loop raced).
// - Stage rows 0-2 of each frame only; row 3 is the constant (0,0,0,1),
//   synthesized at flush. 24 float4/lane, LSTRIDE 25 -> 25.6 KB -> 6 blk/CU
//   (r3 staged 32 -> 33.8 KB -> 4 blk/CU). More blocks/CU = more cross-block
//   overlap of compute with store drain.
// - Flush: 32 fully-contiguous 1 KB wave stores (dense 32 KB span), with
//   lane-constant LDS addressing (64 % 32 == 0 -> per-lane frame/row fixed).

#define LSTRIDE 25  // 24 payload float4 + 1 pad

namespace {

struct V3 { float x, y, z; };
__device__ __forceinline__ V3 v3(float x, float y, float z) { return {x, y, z}; }

__device__ __forceinline__ void stage3(float4* p, V3 c0, V3 c1, V3 c2, V3 c3) {
    p[0] = make_float4(c0.x, c1.x, c2.x, c3.x);
    p[1] = make_float4(c0.y, c1.y, c2.y, c3.y);
    p[2] = make_float4(c0.z, c1.z, c2.z, c3.z);
}

} // namespace

__global__ __launch_bounds__(64) void fk_chain_kernel(const float* __restrict__ q,
                                                      float4* __restrict__ out,
                                                      int n)
{
    __shared__ float4 lds[64 * LSTRIDE];  // 25,600 B

    const int lane = threadIdx.x;                     // block == 1 wave
    const long long e0 = (long long)blockIdx.x * 64;  // group's first element
    long long i = e0 + lane;
    if (i >= n) i = n - 1;                            // clamp; stores guarded

    const float* qi = q + i * 7;
    const float HPI = 1.57079632679489662f;

    float qv[7];
    #pragma unroll
    for (int k = 0; k < 7; ++k) qv[k] = qi[k];

    float c[7], s[7];
    __sincosf(qv[0], &s[0], &c[0]);
    __sincosf(qv[1], &s[1], &c[1]);
    __sincosf(qv[2] - HPI, &s[2], &c[2]);
    __sincosf(qv[3], &s[3], &c[3]);
    __sincosf(qv[4], &s[4], &c[4]);
    __sincosf(qv[5] + HPI, &s[5], &c[5]);
    __sincosf(qv[6] - HPI, &s[6], &c[6]);

    float4* myS = lds + lane * LSTRIDE;

    // chain state: columns of current frame (bottom row implicit)
    V3 f0 = v3(c[0], s[0], 0.f);
    V3 f1 = v3(-s[0], c[0], 0.f);
    V3 f2 = v3(0.f, 0.f, 1.f);
    V3 f3 = v3(0.f, 0.f, 0.f);

    #define TYPE_A(cc, ss)                                              \
        {                                                               \
            V3 t0 = v3((cc)*f0.x + (ss)*f2.x, (cc)*f0.y + (ss)*f2.y, (cc)*f0.z + (ss)*f2.z); \
            V3 t1 = v3((cc)*f2.x - (ss)*f0.x, (cc)*f2.y - (ss)*f0.y, (cc)*f2.z - (ss)*f0.z); \
            V3 t2 = v3(-f1.x, -f1.y, -f1.z);                            \
            f0 = t0; f1 = t1; f2 = t2;                                  \
        }

    stage3(myS + 0, f0, f1, f2, f3);                     // frame 0 = m0

    TYPE_A(c[1], s[1]);                                  // m1
    stage3(myS + 3, f0, f1, f2, f3);

    // m2: f0' = c*f0 - s*f2; f1' = -(s*f0 + c*f2); f2' = f1; f3 += 0.4*f1
    {
        V3 t0 = v3(c[2]*f0.x - s[2]*f2.x, c[2]*f0.y - s[2]*f2.y, c[2]*f0.z - s[2]*f2.z);
        V3 t1 = v3(-(s[2]*f0.x + c[2]*f2.x), -(s[2]*f0.y + c[2]*f2.y), -(s[2]*f0.z + c[2]*f2.z));
        V3 t2 = f1;
        f3 = v3(0.4f*f1.x + f3.x, 0.4f*f1.y + f3.y, 0.4f*f1.z + f3.z);
        f0 = t0; f1 = t1; f2 = t2;
    }
    stage3(myS + 6, f0, f1, f2, f3);

    TYPE_A(c[3], s[3]);                                  // m3
    stage3(myS + 9, f0, f1, f2, f3);

    // m4: f0' = s*f2 - c*f0; f1' = s*f0 + c*f2; f2' = f1; f3 += 0.39*f1
    {
        V3 t0 = v3(s[4]*f2.x - c[4]*f0.x, s[4]*f2.y - c[4]*f0.y, s[4]*f2.z - c[4]*f0.z);
        V3 t1 = v3(s[4]*f0.x + c[4]*f2.x, s[4]*f0.y + c[4]*f2.y, s[4]*f0.z + c[4]*f2.z);
        V3 t2 = f1;
        f3 = v3(0.39f*f1.x + f3.x, 0.39f*f1.y + f3.y, 0.39f*f1.z + f3.z);
        f0 = t0; f1 = t1; f2 = t2;
    }
    stage3(myS + 12, f0, f1, f2, f3);

    TYPE_A(c[5], s[5]);                                  // m5
    stage3(myS + 15, f0, f1, f2, f3);

    TYPE_A(c[6], s[6]);                                  // m6
    stage3(myS + 18, f0, f1, f2, f3);

    // m7: f0' = -f0; f1' = f2; f2' = f1; f3 += 0.118*f1
    {
        V3 t0 = v3(-f0.x, -f0.y, -f0.z);
        V3 t1 = f2;
        V3 t2 = f1;
        f3 = v3(0.118f*f1.x + f3.x, 0.118f*f1.y + f3.y, 0.118f*f1.z + f3.z);
        f0 = t0; f1 = t1; f2 = t2;
    }
    stage3(myS + 21, f0, f1, f2, f3);

    #undef TYPE_A

    __syncthreads();  // order all ds_writes before cross-lane ds_reads

    // ---- flush: 32 dense 1 KB wave stores over the group's 32 KB span ----
    // Store j covers float4 span [j*64, (j+1)*64); since 64 % 32 == 0, this
    // lane's within-element float4 index p = lane & 31 is fixed across j.
    const int hi = lane >> 5;             // element parity within a store
    const int p  = lane & 31;
    const int fr = p >> 2;                // frame 0..7
    const int r  = p & 3;                 // row 0..3
    const int rb = hi * LSTRIDE + fr * 3 + ((r == 3) ? 2 : r);
    const bool isr3 = (r == 3);
    const float4 row3 = make_float4(0.f, 0.f, 0.f, 1.f);

    float4* gb = out + e0 * 32;           // 64 elem * 32 float4
    if (e0 + 64 <= (long long)n) {
        #pragma unroll
        for (int j = 0; j < 32; ++j) {
            float4 v = lds[j * (2 * LSTRIDE) + rb];
            if (isr3) v = row3;
            gb[j * 64 + lane] = v;
        }
    } else {
        #pragma unroll
        for (int j = 0; j < 32; ++j) {
            float4 v = lds[j * (2 * LSTRIDE) + rb];
            if (isr3) v = row3;
            if (e0 + (j * 2 + hi) < (long long)n)
                gb[j * 64 + lane] = v;
        }
    }
}

extern "C" void kernel_launch(void* const* d_in, const int* in_sizes, int n_in,
                              void* d_out, int out_size, void* d_ws, size_t ws_size,
                              hipStream_t stream) {
    const float* x = (const float*)d_in[0];
    float* out = (float*)d_out;
    int n = in_sizes[0] / 7;            // 2,000,000 elements
    int grid = (n + 63) >> 6;           // 31,250 one-wave blocks
    fk_chain_kernel<<<grid, 64, 0, stream>>>(x, (float4*)out, n);
}